// Round 1
// baseline (46.103 us; speedup 1.0000x reference)
//
#include <hip/hip_runtime.h>

#define EPS_F 1e-10f

constexpr int N_CLS = 32;
constexpr int B_SZ  = 2048;
constexpr int D_DIM = 1024;

// Block per b (2048 blocks, 256 threads = 4 waves).
// Wave w handles n = w*8 .. w*8+7. Wave-only reductions, no barriers.
__global__ __launch_bounds__(256)
void cosine_sim_kernel(const float* __restrict__ s,
                       const float* __restrict__ target,
                       float* __restrict__ out) {
    const int b    = blockIdx.x;
    const int lane = threadIdx.x & 63;
    const int wave = threadIdx.x >> 6;

    // ---- load target row into registers: 4 x float4 per lane (covers D=1024) ----
    const float4* t4p = reinterpret_cast<const float4*>(target + (size_t)b * D_DIM);
    float4 t[4];
    float ss_t = 0.0f;
#pragma unroll
    for (int j = 0; j < 4; ++j) {
        t[j] = t4p[lane + 64 * j];
        ss_t = fmaf(t[j].x, t[j].x,
               fmaf(t[j].y, t[j].y,
               fmaf(t[j].z, t[j].z,
               fmaf(t[j].w, t[j].w, ss_t))));
    }
    // wave64 butterfly reduce
#pragma unroll
    for (int off = 32; off >= 1; off >>= 1) ss_t += __shfl_xor(ss_t, off, 64);
    const float r_t = 1.0f / sqrtf(fmaxf(ss_t, EPS_F));

    // ---- 8 rows of s per wave ----
    for (int k = 0; k < 8; ++k) {
        const int n = wave * 8 + k;
        const float4* s4p =
            reinterpret_cast<const float4*>(s + ((size_t)n * B_SZ + b) * (size_t)D_DIM);
        float dot = 0.0f, ss = 0.0f;
#pragma unroll
        for (int j = 0; j < 4; ++j) {
            const float4 v = s4p[lane + 64 * j];
            dot = fmaf(t[j].x, v.x,
                  fmaf(t[j].y, v.y,
                  fmaf(t[j].z, v.z,
                  fmaf(t[j].w, v.w, dot))));
            ss  = fmaf(v.x, v.x,
                  fmaf(v.y, v.y,
                  fmaf(v.z, v.z,
                  fmaf(v.w, v.w, ss))));
        }
#pragma unroll
        for (int off = 32; off >= 1; off >>= 1) {
            dot += __shfl_xor(dot, off, 64);
            ss  += __shfl_xor(ss,  off, 64);
        }
        if (lane == 0) {
            const float r_s = 1.0f / sqrtf(fmaxf(ss, EPS_F));
            out[(size_t)b * N_CLS + n] = dot * r_t * r_s;
        }
    }
}

extern "C" void kernel_launch(void* const* d_in, const int* in_sizes, int n_in,
                              void* d_out, int out_size, void* d_ws, size_t ws_size,
                              hipStream_t stream) {
    const float* s      = (const float*)d_in[0];   // [N, B, D] f32
    const float* target = (const float*)d_in[1];   // [B, D] f32
    // d_in[2] = s_label (int64) — unused by the reference output.
    float* out = (float*)d_out;                    // [B, N] f32

    hipLaunchKernelGGL(cosine_sim_kernel, dim3(B_SZ), dim3(256), 0, stream,
                       s, target, out);
}